// Round 5
// baseline (28.562 us; speedup 1.0000x reference)
//
#include <hip/hip_runtime.h>

#define HALF   16
#define IMW    512
#define IMH    512
#define SH     32              // strip height: rows per block
#define NSTRIP (IMH / SH)      // 16 strips per image
#define NSUB   16              // 32-px-wide subtiles per strip
#define CAP    64              // per-subtile landmark list capacity

typedef float f32x4 __attribute__((ext_vector_type(4)));

// One block per 512x32 strip (64 KB contiguous output). Phase 1: bin the
// image's 106 landmarks (L2-resident) into 16 per-subtile LDS lists (a
// landmark's 33x33 patch touches <=2 subtile columns and this strip iff
// i1 in [R-16, R+47]). Phase 2: dense predicated 32x32-subtile compute,
// 4 px/thread, results into an LDS strip buffer (same bank pattern as a
// linear b128 write -> conflict-free). Phase 3: stream the strip to global
// linearly -- 4 KB contiguous per store instruction, 64 KB per block --
// so DRAM sees streaming writes instead of 128-B scatter at 2-KB stride.
__global__ __launch_bounds__(256)
void lm_strip_kernel(const float* __restrict__ landmarks,  // [B, L, 2]
                     float* __restrict__ out,              // [B, IMH*IMW]
                     int L)
{
    __shared__ float  sbuf[SH][IMW];       // 64 KB strip accumulator
    __shared__ float2 slist[NSUB][CAP];    // 8 KB landmark lists
    __shared__ int    scnt[NSUB];

    const int t  = threadIdx.x;
    const int bx = blockIdx.x;
    const int b  = bx >> 4;                // NSTRIP == 16
    const int ty = bx & (NSTRIP - 1);
    const int R  = ty * SH;                // first row of this strip

    if (t < NSUB) scnt[t] = 0;
    __syncthreads();

    // Phase 1: one thread per landmark (L=106 <= 256; loop for generality).
    const float2* lmb = reinterpret_cast<const float2*>(landmarks) + (size_t)b * L;
    for (int j = t; j < L; j += 256) {
        float2 lm = lmb[j];
        float x0 = fminf(fmaxf(lm.x, (float)HALF), (float)(IMW - 1 - HALF));
        float x1 = fminf(fmaxf(lm.y, (float)HALF), (float)(IMH - 1 - HALF));
        int i0 = (int)x0;                  // coords >= 16 > 0, trunc == floor
        int i1 = (int)x1;
        // patch rows [i1-16, i1+16] overlap strip [R, R+SH) iff i1 in [R-16, R+SH+15]
        if ((unsigned)(i1 - (R - HALF)) < (unsigned)(SH + 2 * HALF)) {
            int sx0 = (i0 - HALF) >> 5;    // patch cols touch subtiles {sx0, sx1}
            int sx1 = (i0 + HALF) >> 5;
            int p0 = atomicAdd(&scnt[sx0], 1);
            if (p0 < CAP) slist[sx0][p0] = make_float2(x0, x1);
            if (sx1 != sx0) {
                int p1 = atomicAdd(&scnt[sx1], 1);
                if (p1 < CAP) slist[sx1][p1] = make_float2(x0, x1);
            }
        }
    }
    __syncthreads();

    // Phase 2: per subtile, 4 contiguous px per thread, dense predicated.
    const int   r   = t >> 3;              // row within strip, 0..31
    const int   c0  = (t & 7) * 4;         // col base within subtile
    const int   py  = R + r;
    const float fpy = (float)py;

    for (int tx = 0; tx < NSUB; ++tx) {
        const int n   = min(scnt[tx], CAP);
        const int px0 = tx * 32 + c0;
        float acc[4] = {0.0f, 0.0f, 0.0f, 0.0f};
        for (int j = 0; j < n; ++j) {
            float2 e = slist[tx][j];       // broadcast read, conflict-free
            int   i0   = (int)e.x;
            int   i1   = (int)e.y;
            float dy   = fpy - e.y;
            float dy2e = dy * dy + 1e-6f;
            bool  in1  = (unsigned)(py - i1 + HALF) <= (unsigned)(2 * HALF);
            #pragma unroll
            for (int c = 0; c < 4; ++c) {
                int   px  = px0 + c;
                float dx  = (float)px - e.x;
                bool  in0 = (unsigned)(px - i0 + HALF) <= (unsigned)(2 * HALF);
                // val = 1/(1+sqrt(d2)); hw sqrt+rcp ~1 ulp, threshold 4.3e-2
                float v = __builtin_amdgcn_rcpf(1.0f + __builtin_amdgcn_sqrtf(dx * dx + dy2e));
                acc[c] += (in0 && in1) ? v : 0.0f;
            }
        }
        f32x4 v4 = { acc[0], acc[1], acc[2], acc[3] };
        *reinterpret_cast<f32x4*>(&sbuf[r][px0]) = v4;
    }
    __syncthreads();

    // Phase 3: stream the 64-KB strip to global. Per instruction the block
    // writes 4 KB contiguous; per block 64 KB contiguous; consecutive blocks
    // cover consecutive 64-KB regions.
    float*       op = out + (size_t)b * (IMH * IMW) + (size_t)R * IMW;
    const float* sp = &sbuf[0][0];
    #pragma unroll
    for (int s = 0; s < 16; ++s) {
        f32x4 v = *reinterpret_cast<const f32x4*>(sp + s * 1024 + t * 4);
        __builtin_nontemporal_store(v, reinterpret_cast<f32x4*>(op + s * 1024 + t * 4));
    }
}

extern "C" void kernel_launch(void* const* d_in, const int* in_sizes, int n_in,
                              void* d_out, int out_size, void* d_ws, size_t ws_size,
                              hipStream_t stream)
{
    // d_in[0] = img (unused by the reference); d_in[1] = landmarks [B, L, 2] f32
    const float* landmarks = (const float*)d_in[1];
    float* out = (float*)d_out;

    const int B = out_size / (IMH * IMW);   // 64
    const int L = in_sizes[1] / (2 * B);    // 106

    lm_strip_kernel<<<B * NSTRIP, 256, 0, stream>>>(landmarks, out, L);
}

// Round 6
// 24.509 us; speedup vs baseline: 1.1654x; 1.1654x over previous
//
#include <hip/hip_runtime.h>

#define HALF 16
#define IMW  512
#define IMH  512
#define TW   64                // tile width
#define TH   32                // tile height
#define NTX  (IMW / TW)        // 8 tile columns
#define NTY  (IMH / TH)        // 16 tile rows
#define TPI  (NTX * NTY)       // 128 tiles per image
#define CAP  64                // landmark list capacity (avg n ~2.5, uniform)

typedef float f32x4 __attribute__((ext_vector_type(4)));

// One block per 64x32 output tile, 8 contiguous px per thread in one row.
// Phase 1: scan the image's 106 landmarks (L2-resident) into one LDS list of
// those whose 33x33 patch intersects this tile (window (64+32)x(32+32) px --
// the minimal-area window for a 2048-px tile). Phase 2: dense predicated
// eval, dy^2+eps hoisted across the thread's 8 columns. Phase 3: two aligned
// b128 nontemporal stores; each 8-lane group covers 256 B contiguous.
__global__ __launch_bounds__(256)
void lm_gather64_kernel(const float* __restrict__ landmarks,  // [B, L, 2]
                        float* __restrict__ out,              // [B, IMH*IMW]
                        int L)
{
    __shared__ float2 slm[CAP];
    __shared__ int sn;

    const int t    = threadIdx.x;
    const int bx   = blockIdx.x;
    const int b    = bx >> 7;            // TPI == 128
    const int tile = bx & (TPI - 1);
    const int tx   = tile & (NTX - 1);
    const int ty   = tile >> 3;
    const int C    = tx * TW;            // first col of tile
    const int R    = ty * TH;            // first row of tile

    if (t == 0) sn = 0;
    __syncthreads();

    // Phase 1: gather this tile's landmarks into LDS.
    const float2* lmb = reinterpret_cast<const float2*>(landmarks) + (size_t)b * L;
    for (int j = t; j < L; j += 256) {
        float2 lm = lmb[j];
        float x0 = fminf(fmaxf(lm.x, (float)HALF), (float)(IMW - 1 - HALF));
        float x1 = fminf(fmaxf(lm.y, (float)HALF), (float)(IMH - 1 - HALF));
        int i0 = (int)x0;                // coords >= 16 > 0, trunc == floor
        int i1 = (int)x1;
        // patch [i0-16,i0+16]x[i1-16,i1+16] intersects tile [C,C+64)x[R,R+32)
        bool hit = (unsigned)(i0 - (C - HALF)) < (unsigned)(TW + 2 * HALF)
                && (unsigned)(i1 - (R - HALF)) < (unsigned)(TH + 2 * HALF);
        if (hit) {
            int pos = atomicAdd(&sn, 1); // LDS atomic, ~2.5 contenders avg
            if (pos < CAP) slm[pos] = make_float2(x0, x1);
        }
    }
    __syncthreads();
    const int n = min(sn, CAP);

    // Phase 2: 8 contiguous pixels per thread, one row.
    const int   py  = R + (t >> 3);
    const int   px0 = C + (t & 7) * 8;
    const float fpy = (float)py;

    float acc[8] = {0, 0, 0, 0, 0, 0, 0, 0};
    for (int j = 0; j < n; ++j) {
        float2 e = slm[j];               // broadcast read, conflict-free
        int   i0   = (int)e.x;
        int   i1   = (int)e.y;
        float dy   = fpy - e.y;
        float dy2e = dy * dy + 1e-6f;
        bool  in1  = (unsigned)(py - i1 + HALF) <= (unsigned)(2 * HALF);
        #pragma unroll
        for (int c = 0; c < 8; ++c) {
            int   px  = px0 + c;
            float dx  = (float)px - e.x;
            bool  in0 = (unsigned)(px - i0 + HALF) <= (unsigned)(2 * HALF);
            // val = 1/(1+sqrt(d2)); hw sqrt+rcp ~1 ulp, threshold 4.3e-2
            float v = __builtin_amdgcn_rcpf(1.0f + __builtin_amdgcn_sqrtf(dx * dx + dy2e));
            acc[c] += (in0 && in1) ? v : 0.0f;
        }
    }

    // Phase 3: two aligned 16B nontemporal stores (32 B/lane).
    float* op = out + (size_t)b * (IMH * IMW) + (size_t)py * IMW + px0;
    f32x4 v0 = { acc[0], acc[1], acc[2], acc[3] };
    f32x4 v1 = { acc[4], acc[5], acc[6], acc[7] };
    __builtin_nontemporal_store(v0, reinterpret_cast<f32x4*>(op));
    __builtin_nontemporal_store(v1, reinterpret_cast<f32x4*>(op) + 1);
}

extern "C" void kernel_launch(void* const* d_in, const int* in_sizes, int n_in,
                              void* d_out, int out_size, void* d_ws, size_t ws_size,
                              hipStream_t stream)
{
    // d_in[0] = img (unused by the reference); d_in[1] = landmarks [B, L, 2] f32
    const float* landmarks = (const float*)d_in[1];
    float* out = (float*)d_out;

    const int B = out_size / (IMH * IMW);   // 64
    const int L = in_sizes[1] / (2 * B);    // 106

    lm_gather64_kernel<<<B * TPI, 256, 0, stream>>>(landmarks, out, L);
}

// Round 7
// 24.362 us; speedup vs baseline: 1.1724x; 1.0060x over previous
//
#include <hip/hip_runtime.h>

#define HALF 16
#define IMW  512
#define IMH  512
#define TW   64                // tile width
#define TH   32                // tile height
#define NTX  (IMW / TW)        // 8 tile columns
#define NTY  (IMH / TH)        // 16 tile rows
#define TPI  (NTX * NTY)       // 128 tiles per image
#define CAP  64                // landmark list capacity (avg n ~2.5, uniform)

typedef float f32x4 __attribute__((ext_vector_type(4)));

// r6 kernel + two changes (clean A/B vs round 6):
//  1. XCD-chunked block swizzle (T1, bijective: 8192 % 8 == 0): XCD x owns
//     the contiguous 8-MB output range (images 8x..8x+7), so each per-XCD L2
//     aggregates dirty write lines from ONE narrow window and streams them
//     out fill-like, instead of every L2 holding lines scattered over all
//     67 MB (DRAM row/bank thrash theory for the 3.4 vs 6.7 TB/s write gap).
//  2. Cached (not nontemporal) stores, so L2 actually does the aggregation.
__global__ __launch_bounds__(256)
void lm_gather64_kernel(const float* __restrict__ landmarks,  // [B, L, 2]
                        float* __restrict__ out,              // [B, IMH*IMW]
                        int L)
{
    __shared__ float2 slm[CAP];
    __shared__ int sn;

    const int t   = threadIdx.x;
    // XCD-chunked swizzle: hw round-robins blockIdx across 8 XCDs; remap so
    // XCD (bx&7) gets contiguous work-ids [1024*(bx&7), +1024).
    const int bx  = (blockIdx.x & 7) * 1024 + (blockIdx.x >> 3);
    const int b    = bx >> 7;            // TPI == 128
    const int tile = bx & (TPI - 1);
    const int tx   = tile & (NTX - 1);
    const int ty   = tile >> 3;
    const int C    = tx * TW;            // first col of tile
    const int R    = ty * TH;            // first row of tile

    if (t == 0) sn = 0;
    __syncthreads();

    // Phase 1: gather this tile's landmarks into LDS.
    const float2* lmb = reinterpret_cast<const float2*>(landmarks) + (size_t)b * L;
    for (int j = t; j < L; j += 256) {
        float2 lm = lmb[j];
        float x0 = fminf(fmaxf(lm.x, (float)HALF), (float)(IMW - 1 - HALF));
        float x1 = fminf(fmaxf(lm.y, (float)HALF), (float)(IMH - 1 - HALF));
        int i0 = (int)x0;                // coords >= 16 > 0, trunc == floor
        int i1 = (int)x1;
        // patch [i0-16,i0+16]x[i1-16,i1+16] intersects tile [C,C+64)x[R,R+32)
        bool hit = (unsigned)(i0 - (C - HALF)) < (unsigned)(TW + 2 * HALF)
                && (unsigned)(i1 - (R - HALF)) < (unsigned)(TH + 2 * HALF);
        if (hit) {
            int pos = atomicAdd(&sn, 1); // LDS atomic, ~2.5 contenders avg
            if (pos < CAP) slm[pos] = make_float2(x0, x1);
        }
    }
    __syncthreads();
    const int n = min(sn, CAP);

    // Phase 2: 8 contiguous pixels per thread, one row.
    const int   py  = R + (t >> 3);
    const int   px0 = C + (t & 7) * 8;
    const float fpy = (float)py;

    float acc[8] = {0, 0, 0, 0, 0, 0, 0, 0};
    for (int j = 0; j < n; ++j) {
        float2 e = slm[j];               // broadcast read, conflict-free
        int   i0   = (int)e.x;
        int   i1   = (int)e.y;
        float dy   = fpy - e.y;
        float dy2e = dy * dy + 1e-6f;
        bool  in1  = (unsigned)(py - i1 + HALF) <= (unsigned)(2 * HALF);
        #pragma unroll
        for (int c = 0; c < 8; ++c) {
            int   px  = px0 + c;
            float dx  = (float)px - e.x;
            bool  in0 = (unsigned)(px - i0 + HALF) <= (unsigned)(2 * HALF);
            // val = 1/(1+sqrt(d2)); hw sqrt+rcp ~1 ulp, threshold 4.3e-2
            float v = __builtin_amdgcn_rcpf(1.0f + __builtin_amdgcn_sqrtf(dx * dx + dy2e));
            acc[c] += (in0 && in1) ? v : 0.0f;
        }
    }

    // Phase 3: two aligned 16B CACHED stores (32 B/lane) — let L2 aggregate.
    float* op = out + (size_t)b * (IMH * IMW) + (size_t)py * IMW + px0;
    f32x4 v0 = { acc[0], acc[1], acc[2], acc[3] };
    f32x4 v1 = { acc[4], acc[5], acc[6], acc[7] };
    reinterpret_cast<f32x4*>(op)[0] = v0;
    reinterpret_cast<f32x4*>(op)[1] = v1;
}

extern "C" void kernel_launch(void* const* d_in, const int* in_sizes, int n_in,
                              void* d_out, int out_size, void* d_ws, size_t ws_size,
                              hipStream_t stream)
{
    // d_in[0] = img (unused by the reference); d_in[1] = landmarks [B, L, 2] f32
    const float* landmarks = (const float*)d_in[1];
    float* out = (float*)d_out;

    const int B = out_size / (IMH * IMW);   // 64
    const int L = in_sizes[1] / (2 * B);    // 106

    lm_gather64_kernel<<<B * TPI, 256, 0, stream>>>(landmarks, out, L);
}